// Round 5
// baseline (40.458 us; speedup 1.0000x reference)
//
#include <hip/hip_runtime.h>
#include <hip/hip_bf16.h>
#include <math.h>

#define NCONF  256
#define NATOMS 128
#define NATOT  (NCONF * NATOMS)
#define PER_ATOM 1216        // 9*64 + 4*64 + 6*64
#define NQUAD  304           // PER_ATOM / 4
#define QS     76            // quads handled per thread-slot stride (NQUAD/4)
#define TOTQ   (NATOT * NQUAD)
#define PSTR   25            // 13 chan + 6 A + 6 B
#define WS_FLOATS (128 + NATOT * PSTR)

// constants: K = 8*log2(e); SQK = sqrt(K); hs = 2^(-7/8) / 2
#define SQK      3.3972871196167196f
#define SK_STEP  0.32355115424921137f   // SQK * 6/63
#define SK_BASE -10.191861358850159f    // -3 * SQK
#define HS       0.27262693316631437f

__device__ __forceinline__ int species_to_sidx(int z) {
    switch (z) {
        case 1:  return 0;
        case 6:  return 1;
        case 7:  return 2;
        case 8:  return 3;
        case 9:  return 4;
        case 16: return 5;
        default: return 6;   // 17
    }
}

// ---------------- Kernel P: per-atom params (one thread per atom), SoA -----
__global__ __launch_bounds__(256) void aev_params_kernel(
    const float* __restrict__ coeff,   // (NATOT, 21)
    const float* __restrict__ nlib,    // (4, 7, 9)
    const int*   __restrict__ sp32,    // int32 or int64 (runtime-detected)
    float* __restrict__ ws)            // [0..127] cos/sin shfT, then SoA params
{
    const int tid  = threadIdx.x;
    const int atom = blockIdx.x * blockDim.x + tid;

    if (blockIdx.x == 0 && tid < 64) {
        float t = (float)tid * (float)(M_PI / 63.0);
        ws[tid]      = cosf(t);
        ws[64 + tid] = sinf(t);
    }
    if (atom >= NATOT) return;

    // species dtype runtime detection: int64 => sp32[1] is high word of
    // species[0] == 0; int32 => sp32[1] in {1,6,7,8,9,16,17} != 0.
    const int is64 = (sp32[1] == 0);
    const int z = is64 ? sp32[(size_t)atom * 2] : sp32[atom];
    const int sidx = species_to_sidx(z);

    const float* c     = coeff + (size_t)atom * 21;
    const float* s_mus = nlib + 0 * 63 + sidx * 9;
    const float* s_sig = nlib + 1 * 63 + sidx * 9;
    const float* p_mus = nlib + 2 * 63 + sidx * 9;
    const float* p_sig = nlib + 3 * 63 + sidx * 9;

    float* P = ws + 128 + atom;   // SoA: param k at P[k * NATOT]

    #pragma unroll
    for (int k = 0; k < 9; ++k)
        P[k * NATOT] = SQK * (c[k] - s_mus[k]) / s_sig[k];

    float M[4][3];
    #pragma unroll
    for (int i = 0; i < 4; ++i) {
        M[i][0] = c[9 + i * 3 + 0];
        M[i][1] = c[9 + i * 3 + 1];
        M[i][2] = c[9 + i * 3 + 2];
        float nn  = M[i][0]*M[i][0] + M[i][1]*M[i][1] + M[i][2]*M[i][2];
        float nrm = sqrtf(nn);
        bool zero = (fabsf(M[i][0]) < 1e-12f) &&
                    (fabsf(M[i][1]) < 1e-12f) &&
                    (fabsf(M[i][2]) < 1e-12f);
        P[(9 + i) * NATOT] = SQK * (nrm - p_mus[i]) / p_sig[i];
        float inv = zero ? 0.0f : (1.0f / nrm);
        M[i][0] *= inv; M[i][1] *= inv; M[i][2] *= inv;
    }
    const int iu[6] = {0, 0, 0, 1, 1, 2};
    const int ju[6] = {1, 2, 3, 2, 3, 3};
    #pragma unroll
    for (int p = 0; p < 6; ++p) {
        int i = iu[p], j = ju[p];
        float d = M[i][0]*M[j][0] + M[i][1]*M[j][1] + M[i][2]*M[j][2];
        d = fminf(fmaxf(d, -0.9999f), 0.9999f);
        float sa = sqrtf(fmaxf(1.0f - d * d, 0.0f));
        P[(13 + p) * NATOT] = HS * d;    // A
        P[(19 + p) * NATOT] = HS * sa;   // B
    }
}

// ---------------- Kernel S: streaming, 4 quads (64B) per thread ------------
__global__ __launch_bounds__(256) void aev_stream_kernel(
    const float* __restrict__ ws,
    float* __restrict__ out)
{
    const int g = blockIdx.x * 256 + threadIdx.x;   // 0 .. NATOT*QS-1
    const int atom = g / QS;                        // magic-mul division
    const int r    = g - atom * QS;

    const float* P = ws + 128 + atom;
    float* po = out + (size_t)atom * PER_ATOM;

    #pragma unroll
    for (int k = 0; k < 4; ++k) {
        const int q  = r + k * QS;
        const int ch = q >> 4;              // channel 0..18
        const int j0 = (q & 15) << 2;       // bin base 0..60
        float vv[4];
        if (ch < 13) {
            // exp2(-(X - SQK*shf_j)^2), X = SQK * normalized coord
            const float X = P[ch * NATOT];
            #pragma unroll
            for (int jj = 0; jj < 4; ++jj) {
                float d = X - fmaf((float)(j0 + jj), SK_STEP, SK_BASE);
                vv[jj] = exp2f(-(d * d));
            }
        } else {
            // (HS + A*cos(t_j) + B*sin(t_j))^8
            const int p = ch - 13;
            const float A = P[(13 + p) * NATOT];
            const float B = P[(19 + p) * NATOT];
            const float4 ct = *reinterpret_cast<const float4*>(ws + j0);
            const float4 st = *reinterpret_cast<const float4*>(ws + 64 + j0);
            const float cts[4] = {ct.x, ct.y, ct.z, ct.w};
            const float sts[4] = {st.x, st.y, st.z, st.w};
            #pragma unroll
            for (int jj = 0; jj < 4; ++jj) {
                float u  = fmaf(A, cts[jj], fmaf(B, sts[jj], HS));
                float u2 = u * u;
                float u4 = u2 * u2;
                vv[jj] = u4 * u4;
            }
        }
        float4 v; v.x = vv[0]; v.y = vv[1]; v.z = vv[2]; v.w = vv[3];
        *reinterpret_cast<float4*>(po + q * 4) = v;
    }
}

// ---------------- Fallback: proven round-4 monolithic kernel ---------------
__global__ __launch_bounds__(256) void aev_mono_kernel(
    const float* __restrict__ coeff,
    const float* __restrict__ nlib,
    const int*   __restrict__ sp32,
    float* __restrict__ out)
{
    __shared__ float s_chan[13];
    __shared__ float s_ca[6], s_sa[6];
    __shared__ float s_ct[64], s_st[64];

    const int atom = blockIdx.x;
    const int tid  = threadIdx.x;

    if (tid < 64) {
        float t = (float)tid * (float)(M_PI / 63.0);
        s_ct[tid] = cosf(t);
        s_st[tid] = sinf(t);
    }
    if (tid == 0) {
        const float* c = coeff + (size_t)atom * 21;
        const int is64 = (sp32[1] == 0);
        const int z = is64 ? sp32[(size_t)atom * 2] : sp32[atom];
        const int sidx = species_to_sidx(z);
        const float* s_mus = nlib + 0 * 63 + sidx * 9;
        const float* s_sig = nlib + 1 * 63 + sidx * 9;
        const float* p_mus = nlib + 2 * 63 + sidx * 9;
        const float* p_sig = nlib + 3 * 63 + sidx * 9;
        #pragma unroll
        for (int k = 0; k < 9; ++k)
            s_chan[k] = (c[k] - s_mus[k]) / s_sig[k];
        float M[4][3];
        #pragma unroll
        for (int i = 0; i < 4; ++i) {
            M[i][0] = c[9+i*3+0]; M[i][1] = c[9+i*3+1]; M[i][2] = c[9+i*3+2];
            float nn  = M[i][0]*M[i][0] + M[i][1]*M[i][1] + M[i][2]*M[i][2];
            float nrm = sqrtf(nn);
            bool zero = (fabsf(M[i][0]) < 1e-12f) && (fabsf(M[i][1]) < 1e-12f) &&
                        (fabsf(M[i][2]) < 1e-12f);
            s_chan[9+i] = (nrm - p_mus[i]) / p_sig[i];
            float inv = zero ? 0.0f : (1.0f / nrm);
            M[i][0] *= inv; M[i][1] *= inv; M[i][2] *= inv;
        }
        const int iu[6] = {0,0,0,1,1,2};
        const int ju[6] = {1,2,3,2,3,3};
        #pragma unroll
        for (int p = 0; p < 6; ++p) {
            int i = iu[p], j = ju[p];
            float d = M[i][0]*M[j][0] + M[i][1]*M[j][1] + M[i][2]*M[j][2];
            d = fminf(fmaxf(d, -0.9999f), 0.9999f);
            s_ca[p] = d;
            s_sa[p] = sqrtf(fmaxf(1.0f - d*d, 0.0f));
        }
    }
    __syncthreads();

    float* po = out + (size_t)atom * PER_ATOM;
    const float K = 11.541560327111707f;
    for (int q = tid; q < NQUAD; q += 256) {
        const int ch = q >> 4;
        const int j0 = (q & 15) << 2;
        float vv[4];
        if (ch < 13) {
            float x = s_chan[ch];
            #pragma unroll
            for (int jj = 0; jj < 4; ++jj) {
                float shf = -3.0f + (float)(j0 + jj) * (6.0f / 63.0f);
                float d = x - shf;
                vv[jj] = exp2f(-K * d * d);
            }
        } else {
            int p = ch - 13;
            float cap = s_ca[p], sap = s_sa[p];
            #pragma unroll
            for (int jj = 0; jj < 4; ++jj) {
                float t  = 0.5f + 0.5f * (cap * s_ct[j0+jj] + sap * s_st[j0+jj]);
                float t2 = t * t;
                float t4 = t2 * t2;
                vv[jj] = 0.0078125f * (t4 * t4);
            }
        }
        float4 v; v.x = vv[0]; v.y = vv[1]; v.z = vv[2]; v.w = vv[3];
        *reinterpret_cast<float4*>(po + q * 4) = v;
    }
}

extern "C" void kernel_launch(void* const* d_in, const int* in_sizes, int n_in,
                              void* d_out, int out_size, void* d_ws, size_t ws_size,
                              hipStream_t stream) {
    const float* coeff   = (const float*)d_in[0];
    const float* nlib    = (const float*)d_in[1];
    const int*   sp32    = (const int*)d_in[2];
    float* out           = (float*)d_out;
    float* ws            = (float*)d_ws;

    if (ws_size >= (size_t)WS_FLOATS * sizeof(float)) {
        aev_params_kernel<<<dim3((NATOT + 255) / 256), dim3(256), 0, stream>>>(
            coeff, nlib, sp32, ws);
        aev_stream_kernel<<<dim3((NATOT * QS) / 256), dim3(256), 0, stream>>>(ws, out);
    } else {
        aev_mono_kernel<<<dim3(NATOT), dim3(256), 0, stream>>>(
            coeff, nlib, sp32, out);
    }
}

// Round 6
// 31.836 us; speedup vs baseline: 1.2708x; 1.2708x over previous
//
#include <hip/hip_runtime.h>
#include <hip/hip_bf16.h>
#include <math.h>

#define NCONF  256
#define NATOMS 128
#define NATOT  (NCONF * NATOMS)
#define PER_ATOM 1216        // 9*64 + 4*64 + 6*64
#define ABLK   16            // atoms per block
#define NBLK   (NATOT / ABLK)   // 2048 blocks = 8 per CU

// constants: K = 8*log2(e); SQK = sqrt(K); HS = 2^(-7/8) / 2
#define SQK      3.3972871196167196f
#define SK_STEP  0.32355115424921137f   // SQK * 6/63
#define SK_BASE -10.191861358850159f    // -3 * SQK
#define HS       0.27262693316631437f

__device__ __forceinline__ int species_to_sidx(int z) {
    switch (z) {
        case 1:  return 0;
        case 6:  return 1;
        case 7:  return 2;
        case 8:  return 3;
        case 9:  return 4;
        case 16: return 5;
        default: return 6;   // 17
    }
}

__global__ __launch_bounds__(256) void aev_fused_kernel(
    const float* __restrict__ coeff,   // (NATOT, 21) f32
    const float* __restrict__ nlib,    // (4, 7, 9) f32
    const int*   __restrict__ sp32,    // species, int32 OR int64 (detected)
    float* __restrict__ out)           // (NATOT, 1216) f32
{
    __shared__ float c_sh[ABLK][21];       // staged coefficients
    __shared__ float pars[ABLK][25];       // X[0..12], A[13..18], B[19..24]
    __shared__ float Mn_sh[ABLK][4][3];    // normalized p-vectors
    __shared__ int   sidx_sh[ABLK];
    __shared__ float ct_sh[64], st_sh[64]; // cos/sin of shfT grid

    const int tid = threadIdx.x;
    const int a0  = blockIdx.x * ABLK;

    // ---- phase 0: table + coalesced coeff staging + species ----
    if (tid < 64) {
        float t = (float)tid * (float)(M_PI / 63.0);
        ct_sh[tid] = __cosf(t);
        st_sh[tid] = __sinf(t);
    }
    #pragma unroll
    for (int i = tid; i < ABLK * 21; i += 256) {     // 336 floats, coalesced
        c_sh[i / 21][i % 21] = coeff[(size_t)a0 * 21 + i];
    }
    if (tid < ABLK) {
        // species dtype runtime detection: int64 => sp32[1] is high word of
        // species[0] == 0; int32 => sp32[1] in {1,6,7,8,9,16,17} != 0.
        const int is64 = (sp32[1] == 0);
        const int atom = a0 + tid;
        const int z = is64 ? sp32[(size_t)atom * 2] : sp32[atom];
        sidx_sh[tid] = species_to_sidx(z);
    }
    __syncthreads();

    // ---- phase 1: s-channels (144 thr) + p-norms (64 thr) ----
    if (tid < 144) {
        int a = tid / 9, k = tid - a * 9;
        int sidx = sidx_sh[a];
        float mu = nlib[0 * 63 + sidx * 9 + k];
        float sg = nlib[1 * 63 + sidx * 9 + k];
        pars[a][k] = SQK * (c_sh[a][k] - mu) / sg;
    } else if (tid < 208) {
        int t = tid - 144;
        int a = t >> 2, i = t & 3;
        float x = c_sh[a][9 + i * 3 + 0];
        float y = c_sh[a][9 + i * 3 + 1];
        float w = c_sh[a][9 + i * 3 + 2];
        float nn  = x * x + y * y + w * w;
        float nrm = sqrtf(nn);
        bool zero = (fabsf(x) < 1e-12f) && (fabsf(y) < 1e-12f) &&
                    (fabsf(w) < 1e-12f);
        int sidx = sidx_sh[a];
        float mu = nlib[2 * 63 + sidx * 9 + i];
        float sg = nlib[3 * 63 + sidx * 9 + i];
        pars[a][9 + i] = SQK * (nrm - mu) / sg;
        float inv = zero ? 0.0f : (1.0f / nrm);
        Mn_sh[a][i][0] = x * inv;
        Mn_sh[a][i][1] = y * inv;
        Mn_sh[a][i][2] = w * inv;
    }
    __syncthreads();

    // ---- phase 2: pair angles (96 thr) ----
    if (tid < 96) {
        int a = tid / 6, p = tid - a * 6;
        const int iu[6] = {0, 0, 0, 1, 1, 2};
        const int ju[6] = {1, 2, 3, 2, 3, 3};
        int i = iu[p], j = ju[p];
        float d = Mn_sh[a][i][0] * Mn_sh[a][j][0] +
                  Mn_sh[a][i][1] * Mn_sh[a][j][1] +
                  Mn_sh[a][i][2] * Mn_sh[a][j][2];
        d = fminf(fmaxf(d, -0.9999f), 0.9999f);
        float sa = sqrtf(fmaxf(1.0f - d * d, 0.0f));
        pars[a][13 + p] = HS * d;    // A
        pars[a][19 + p] = HS * sa;   // B
    }
    __syncthreads();

    float* po_blk = out + (size_t)a0 * PER_ATOM;

    // ---- phase 3a: radial, 16 atoms x 208 quads = 3328 = 13 x 256 (uniform) ----
    #pragma unroll
    for (int it = 0; it < 13; ++it) {
        int idx = it * 256 + tid;
        int a   = idx / 208;             // magic-mul
        int rq  = idx - a * 208;         // quad within atom, 0..207
        float X = pars[a][rq >> 4];
        float b = fmaf((float)((rq & 15) << 2), SK_STEP, SK_BASE);
        float d0 = X - b;
        float d1 = d0 - SK_STEP;
        float d2 = d1 - SK_STEP;
        float d3 = d2 - SK_STEP;
        float4 v;
        v.x = exp2f(-(d0 * d0));
        v.y = exp2f(-(d1 * d1));
        v.z = exp2f(-(d2 * d2));
        v.w = exp2f(-(d3 * d3));
        *reinterpret_cast<float4*>(po_blk + a * PER_ATOM + rq * 4) = v;
    }

    // ---- phase 3b: angular, 16 atoms x 96 quads = 1536 = 6 x 256 (uniform) ----
    #pragma unroll
    for (int it = 0; it < 6; ++it) {
        int idx = it * 256 + tid;
        int a   = idx / 96;              // magic-mul
        int aq  = idx - a * 96;          // 0..95
        int p   = aq >> 4;
        int j0  = (aq & 15) << 2;
        float Ap = pars[a][13 + p];
        float Bp = pars[a][19 + p];
        float4 ct = *reinterpret_cast<const float4*>(&ct_sh[j0]);
        float4 st = *reinterpret_cast<const float4*>(&st_sh[j0]);
        float u0 = fmaf(Ap, ct.x, fmaf(Bp, st.x, HS));
        float u1 = fmaf(Ap, ct.y, fmaf(Bp, st.y, HS));
        float u2 = fmaf(Ap, ct.z, fmaf(Bp, st.z, HS));
        float u3 = fmaf(Ap, ct.w, fmaf(Bp, st.w, HS));
        float4 v;
        u0 *= u0; u0 *= u0; v.x = u0 * u0;   // u^8
        u1 *= u1; u1 *= u1; v.y = u1 * u1;
        u2 *= u2; u2 *= u2; v.z = u2 * u2;
        u3 *= u3; u3 *= u3; v.w = u3 * u3;
        *reinterpret_cast<float4*>(po_blk + a * PER_ATOM + 832 + aq * 4) = v;
    }
}

extern "C" void kernel_launch(void* const* d_in, const int* in_sizes, int n_in,
                              void* d_out, int out_size, void* d_ws, size_t ws_size,
                              hipStream_t stream) {
    const float* coeff   = (const float*)d_in[0];
    const float* nlib    = (const float*)d_in[1];
    const int*   sp32    = (const int*)d_in[2];
    float* out           = (float*)d_out;

    aev_fused_kernel<<<dim3(NBLK), dim3(256), 0, stream>>>(
        coeff, nlib, sp32, out);
}